// Round 4
// baseline (134.583 us; speedup 1.0000x reference)
//
#include <hip/hip_runtime.h>

#define NB   2
#define NCO  8
#define NCI  8
#define ND   8
#define NGH  16
#define NGW  16
#define NH   512
#define NW   512
#define NCHUNK 5   // ceil(35*35 / 256)

// One 256-thread block per (b, cell_y, cell_x, chunk); 1 pixel per thread.
// Cell grid (512 floats) staged in LDS once; epilogue reads it with
// wave-uniform ds_read_b128 (broadcast, conflict-free).
// 2250 blocks x 4 waves = 9000 waves -> ~8.8 waves/SIMD for latency hiding.
__global__ __launch_bounds__(256, 8) void bslice_kernel(
    const float* __restrict__ grid,
    const float* __restrict__ guide,
    const float* __restrict__ inp,
    float* __restrict__ out)
{
    const int tid   = threadIdx.x;
    const int cx    = blockIdx.x;          // 0..14
    const int cy    = blockIdx.y;          // 0..14
    const int bz    = blockIdx.z;          // 0..9
    const int b     = bz & 1;
    const int chunk = bz >> 1;             // 0..4

    // pixel range of this cell: x with min(floor(x*15/511),14) == cx
    const int xs = (cx * (NW - 1) + (NGW - 2)) / (NGW - 1);
    const int xe = (cx == NGW - 2) ? NW : (((cx + 1) * (NW - 1) + (NGW - 2)) / (NGW - 1));
    const int ys = (cy * (NH - 1) + (NGH - 2)) / (NGH - 1);
    const int ye = (cy == NGH - 2) ? NH : (((cy + 1) * (NH - 1) + (NGH - 2)) / (NGH - 1));

    // LDS layout: [co][dy][dx][k][z]; bias (k=1) pre-scaled by 1/8.
    __shared__ float sg[NCO * 64];
    for (int i = tid; i < NCO * 64; i += 256) {
        int z  = i & 7;
        int k  = (i >> 3) & 1;
        int dx = (i >> 4) & 1;
        int dy = (i >> 5) & 1;
        int co = i >> 6;
        float v = grid[((((size_t)(b * NCO + co) * 2 + k) * ND + z) * NGH + (cy + dy)) * NGW + (cx + dx)];
        sg[i] = k ? v * 0.125f : v;
    }
    __syncthreads();

    const unsigned wcell = (unsigned)(xe - xs);
    const int npix = (int)wcell * (ye - ys);

    const int i = chunk * 256 + tid;
    const bool valid = (i < npix);
    const unsigned ii = (unsigned)(valid ? i : (npix - 1));
    const unsigned q  = ii / wcell;
    const int py = ys + (int)q;
    const int px = xs + (int)(ii - q * wcell);

    const float step = (float)(NGH - 1) / (float)(NH - 1);   // 15/511
    const float wy = (float)py * step - (float)cy;           // in (0,1]
    const float wx = (float)px * step - (float)cx;
    float wgt[4];
    wgt[0] = (1.f - wy) * (1.f - wx);
    wgt[1] = (1.f - wy) * wx;
    wgt[2] = wy * (1.f - wx);
    wgt[3] = wy * wx;

    const int off = py * NW + px;
    const size_t inbase = (size_t)b * NCI * NH * NW;

    // z-tent accumulation: S0[z] = sum_ci tent_z * inp, S1[z] = sum_ci tent_z.
    float S0[8], S1[8];
    #pragma unroll
    for (int z = 0; z < 8; ++z) { S0[z] = 0.f; S1[z] = 0.f; }

    const float* gp = guide + inbase + off;
    const float* vp = inp   + inbase + off;
    #pragma unroll
    for (int ci = 0; ci < NCI; ++ci) {
        float g = gp[(size_t)ci * NH * NW];
        float v = vp[(size_t)ci * NH * NW];
        float zp = fminf(fmaxf(g * 7.0f, 0.0f), 7.0f);
        #pragma unroll
        for (int z = 0; z < 8; ++z) {
            float a = fmaxf(0.0f, 1.0f - fabsf(zp - (float)z));
            S0[z] = fmaf(a, v, S0[z]);
            S1[z] += a;
        }
    }

    const size_t obase = (size_t)b * NCO * NH * NW;

    #pragma unroll 1
    for (int co = 0; co < NCO; ++co) {
        float acc = 0.f;
        #pragma unroll
        for (int c = 0; c < 4; ++c) {
            // 16 contiguous dwords for (co, corner c): [k=0 z0..7][k=1(bias/8) z0..7]
            const float4 w0 = *(const float4*)&sg[co * 64 + c * 16 + 0];
            const float4 w1 = *(const float4*)&sg[co * 64 + c * 16 + 4];
            const float4 b0 = *(const float4*)&sg[co * 64 + c * 16 + 8];
            const float4 b1 = *(const float4*)&sg[co * 64 + c * 16 + 12];
            float t;
            t = S0[0] * w0.x;
            t = fmaf(S0[1], w0.y, t);
            t = fmaf(S0[2], w0.z, t);
            t = fmaf(S0[3], w0.w, t);
            t = fmaf(S0[4], w1.x, t);
            t = fmaf(S0[5], w1.y, t);
            t = fmaf(S0[6], w1.z, t);
            t = fmaf(S0[7], w1.w, t);
            t = fmaf(S1[0], b0.x, t);
            t = fmaf(S1[1], b0.y, t);
            t = fmaf(S1[2], b0.z, t);
            t = fmaf(S1[3], b0.w, t);
            t = fmaf(S1[4], b1.x, t);
            t = fmaf(S1[5], b1.y, t);
            t = fmaf(S1[6], b1.z, t);
            t = fmaf(S1[7], b1.w, t);
            acc = fmaf(wgt[c], t, acc);
        }
        if (valid)
            out[obase + (size_t)co * NH * NW + off] = acc;
    }
}

extern "C" void kernel_launch(void* const* d_in, const int* in_sizes, int n_in,
                              void* d_out, int out_size, void* d_ws, size_t ws_size,
                              hipStream_t stream) {
    const float* grid  = (const float*)d_in[0];
    const float* guide = (const float*)d_in[1];
    const float* inp   = (const float*)d_in[2];
    float* out = (float*)d_out;

    dim3 g(NGW - 1, NGH - 1, NB * NCHUNK);   // (15, 15, 10) = 2250 blocks, 9000 waves
    bslice_kernel<<<g, 256, 0, stream>>>(grid, guide, inp, out);
}